// Round 9
// baseline (1644.475 us; speedup 1.0000x reference)
//
#include <hip/hip_runtime.h>

// LSTM B=256, T=2048, H=128, gates 4H=512, deferred fc projection.
// Round-8 lesson: >~50 persistent arch VGPRs per thread ALWAYS get parked
// into AGPRs by the allocator (R2/R3/R5/R6/R8), costing an accvgpr_read per
// VALU use. MFMA sidesteps this: MFMA A/B operands can live in AGPRs
// natively. So the recurrent matvec moves to the matrix pipe.
//
// One batch row per WG (256 WGs), 512 threads = 8 waves. Wave w owns gates
// [64w, 64w+64): 4 N-tiles of v_mfma_f32_16x16x16_f16 (documented gfx908
// layout, still on gfx950): A[m][k]: lane l, elem e -> m=l&15, k=4*(l>>4)+e;
// B[k][n]: k=4*(l>>4)+e, n=l&15; D[m][n]: n=l&15, m=4*(l>>4)+e.
// M dim = batch (only row 0 used: A zero except lanes l&15==0).
// B-frags = W_hh[n][k] slices: 4 tiles x 8 K-chunks x (f16x4) = 64 regs,
// persistent, pinned (AGPR residence is fine - MFMA reads AGPRs directly).
//
// Per step: masked 8x b64 h-reads (4 lanes) -> 32 MFMA (4 indep acc chains)
// -> lanes<16: +bias +x*W_ih, activate (wave-uniform sig/tanh), write G_lds
// -> barrier -> threads<128: cell update, h -> double-buffered h_lds fp16 +
// fire-and-forget global store -> barrier (both lgkmcnt-only, no vmcnt).

typedef _Float16 half2v __attribute__((ext_vector_type(2)));
typedef _Float16 f16x4  __attribute__((ext_vector_type(4)));
typedef float    f32x4  __attribute__((ext_vector_type(4)));

constexpr int NB = 256;
constexpr int NT = 2048;
constexpr int NH = 128;

__device__ __forceinline__ float fexp2(float x) {
    float r;
    asm("v_exp_f32 %0, %1" : "=v"(r) : "v"(x));
    return r;
}
__device__ __forceinline__ float frcp(float x) {
    float r;
    asm("v_rcp_f32 %0, %1" : "=v"(r) : "v"(x));
    return r;
}
__device__ __forceinline__ float fsig(float x) {   // 1/(1+2^(-x*log2e))
    return frcp(1.f + fexp2(x * -1.44269504f));
}
__device__ __forceinline__ float ftanh(float x) {  // 2/(1+2^(-2x*log2e)) - 1
    return fmaf(2.f, frcp(1.f + fexp2(x * -2.88539008f)), -1.f);
}

__device__ __forceinline__ unsigned packh2(float lo, float hi) {
    half2v p;
    p.x = (_Float16)lo;
    p.y = (_Float16)hi;
    return __builtin_bit_cast(unsigned, p);
}

__device__ __forceinline__ float dot2(unsigned int w, unsigned int h, float acc) {
    half2v a = __builtin_bit_cast(half2v, w);
    half2v b = __builtin_bit_cast(half2v, h);
#if __has_builtin(__builtin_amdgcn_fdot2)
    return __builtin_amdgcn_fdot2(a, b, acc, false);
#else
    float r;
    asm("v_dot2_f32_f16 %0, %1, %2, %3" : "=v"(r) : "v"(a), "v"(b), "v"(acc));
    return r;
#endif
}

__device__ __forceinline__ f32x4 mfma16(f16x4 a, f16x4 b, f32x4 c) {
#if __has_builtin(__builtin_amdgcn_mfma_f32_16x16x16f16)
    return __builtin_amdgcn_mfma_f32_16x16x16f16(a, b, c, 0, 0, 0);
#else
    asm("v_mfma_f32_16x16x16_f16 %0, %1, %2, %0" : "+v"(c) : "v"(a), "v"(b));
    return c;
#endif
}

// barrier with LDS visibility, NO vmcnt drain (fire-and-forget h stores
// stay off the 2048-iteration critical path)
__device__ __forceinline__ void barrier_lds() {
    asm volatile("s_waitcnt lgkmcnt(0)" ::: "memory");
    __builtin_amdgcn_s_barrier();
    asm volatile("" ::: "memory");
}

template <bool DEFER_FC>
__global__ __launch_bounds__(512, 2)
void lstm_k1(const float* __restrict__ x, const float* __restrict__ W_ih,
             const float* __restrict__ W_hh, const float* __restrict__ b_ih,
             const float* __restrict__ b_hh, const float* __restrict__ fc_w,
             const float* __restrict__ fc_b, float* __restrict__ out,
             _Float16* __restrict__ hws) {
    __shared__ __align__(16) float    x_lds[NT];
    __shared__ __align__(16) _Float16 h_lds[2][NH];  // double buffer
    __shared__ __align__(16) float    g_lds[4 * NH]; // activated gates
    __shared__ float red[2];                         // fallback fc partials

    const int b    = blockIdx.x;
    const int t    = threadIdx.x;   // 0..511
    const int lane = t & 63;
    const int w    = t >> 6;        // wave 0..7: gates [64w, 64w+64)
    const int q    = lane >> 4;     // k-subgroup 0..3
    const int nlo  = lane & 15;     // column-within-tile

    // preload x row (512 x float4)
    ((float4*)x_lds)[t] = ((const float4*)(x + (size_t)b * NT))[t];
    if (t < NH) h_lds[0][t] = (_Float16)0.f;

    // ---- persistent B-frags: W_hh[n][k] for 4 N-tiles x 8 K-chunks ----
    // lane l, elem e of bw[tile][kc] = W_hh[64w+16*tile+nlo][16*kc+4*q+e]
    f16x4 bw[4][8];
#pragma unroll
    for (int tile = 0; tile < 4; ++tile) {
        const float* wrow = W_hh + (size_t)(64 * w + 16 * tile + nlo) * NH;
#pragma unroll
        for (int kc = 0; kc < 8; ++kc) {
            float4 f = *(const float4*)(wrow + kc * 16 + q * 4);
            f16x4 v;
            v[0] = (_Float16)f.x;
            v[1] = (_Float16)f.y;
            v[2] = (_Float16)f.z;
            v[3] = (_Float16)f.w;
            bw[tile][kc] = v;
        }
    }
#pragma unroll
    for (int tile = 0; tile < 4; ++tile)
#pragma unroll
        for (int kc = 0; kc < 8; ++kc) asm volatile("" : "+v"(bw[tile][kc]));

    // per-lane gate constants (extract lanes only): gate g = 64w+16*tile+lane
    float wih0 = 0.f, wih1 = 0.f, wih2 = 0.f, wih3 = 0.f;
    float bia0 = 0.f, bia1 = 0.f, bia2 = 0.f, bia3 = 0.f;
    if (lane < 16) {
        const int g0 = 64 * w + lane;
        wih0 = W_ih[g0];
        wih1 = W_ih[g0 + 16];
        wih2 = W_ih[g0 + 32];
        wih3 = W_ih[g0 + 48];
        bia0 = b_ih[g0] + b_hh[g0];
        bia1 = b_ih[g0 + 16] + b_hh[g0 + 16];
        bia2 = b_ih[g0 + 32] + b_hh[g0 + 32];
        bia3 = b_ih[g0 + 48] + b_hh[g0 + 48];
    }
    const bool is_tanh = (w == 4) || (w == 5);  // gates 256..383 = z

    float c = 0.f, h = 0.f;  // cell state: threads t<128 own unit u=t
    float fcw = 0.f, fcb = 0.f;
    if (!DEFER_FC && t < NH) {
        fcw = fc_w[t];
        fcb = fc_b[0];
    }

    float*    outp = out + (size_t)b * NT;
    _Float16* hrow = DEFER_FC ? (hws + (size_t)b * NT * NH) : (_Float16*)nullptr;

    // A-frags: zero except lanes nlo==0 (batch row 0), refreshed each step
    f16x4 av[8];
#pragma unroll
    for (int kc = 0; kc < 8; ++kc) av[kc] = f16x4{0, 0, 0, 0};

    __syncthreads();

    for (int step = 0; step < NT; ++step) {
        // ---- A-frag load: h[k], k = 16*kc + 4*q + e, on lanes nlo==0 ----
        const _Float16* hbuf = h_lds[step & 1];
        if (nlo == 0) {
#pragma unroll
            for (int kc = 0; kc < 8; ++kc)
                av[kc] = *(const f16x4*)(hbuf + kc * 16 + q * 4);
        }
        // ---- 32 MFMA: 4 independent accumulation chains ----
        f32x4 a0 = {0.f, 0.f, 0.f, 0.f}, a1 = a0, a2 = a0, a3 = a0;
#pragma unroll
        for (int kc = 0; kc < 8; ++kc) {
            a0 = mfma16(av[kc], bw[0][kc], a0);
            a1 = mfma16(av[kc], bw[1][kc], a1);
            a2 = mfma16(av[kc], bw[2][kc], a2);
            a3 = mfma16(av[kc], bw[3][kc], a3);
        }
        // ---- extract row 0 (lanes 0..15, elem 0), activate, -> g_lds ----
        if (lane < 16) {
            float xv = x_lds[step];
            float v0 = fmaf(xv, wih0, a0[0] + bia0);
            float v1 = fmaf(xv, wih1, a1[0] + bia1);
            float v2 = fmaf(xv, wih2, a2[0] + bia2);
            float v3 = fmaf(xv, wih3, a3[0] + bia3);
            float r0, r1, r2, r3;
            if (is_tanh) {
                r0 = ftanh(v0); r1 = ftanh(v1); r2 = ftanh(v2); r3 = ftanh(v3);
            } else {
                r0 = fsig(v0);  r1 = fsig(v1);  r2 = fsig(v2);  r3 = fsig(v3);
            }
            const int g0 = 64 * w + lane;
            g_lds[g0]      = r0;
            g_lds[g0 + 16] = r1;
            g_lds[g0 + 32] = r2;
            g_lds[g0 + 48] = r3;
        }
        barrier_lds();

        // ---- cell update: thread t<128 owns unit u=t ----
        if (t < NH) {
            float gi = g_lds[t];
            float gf = g_lds[NH + t];
            float gz = g_lds[2 * NH + t];
            float go = g_lds[3 * NH + t];
            c = fmaf(gf, c, gi * gz);
            h = go * ftanh(c);
            h_lds[(step + 1) & 1][t] = (_Float16)h;
            if (DEFER_FC) hrow[(size_t)step * NH + t] = (_Float16)h;
        }
        if (!DEFER_FC) {
            if (t < NH) {
                float p = h * fcw;
#pragma unroll
                for (int m = 32; m >= 1; m >>= 1) p += __shfl_xor(p, m, 64);
                if (lane == 0) red[t >> 6] = p;
            }
            __syncthreads();
            if (t == 0) outp[step] = ftanh(red[0] + red[1] + fcb);
        }
        barrier_lds();
    }

    // ---- final hT, cT ([1,B,H] each, after out) ----
    if (t < NH) {
        float* hT = out + (size_t)NB * NT;
        float* cT = hT + (size_t)NB * NH;
        hT[b * NH + t] = h;
        cT[b * NH + t] = c;
    }
}

// Kernel 2: out[b,t] = tanh(dot(h[b,t,:], fc_w) + fc_b). Memory-bound.
__global__ __launch_bounds__(256) void fc_k2(const _Float16* __restrict__ hws,
                                             const float* __restrict__ fc_w,
                                             const float* __restrict__ fc_b,
                                             float* __restrict__ out) {
    __shared__ unsigned wlds[64];
    const int t = threadIdx.x;
    if (t < 64) {
        float2 f = ((const float2*)fc_w)[t];
        wlds[t] = packh2(f.x, f.y);
    }
    __syncthreads();

    const size_t idx = (size_t)blockIdx.x * 256 + t;
    const uint4* hp = (const uint4*)(hws + idx * NH);
    const uint4* wp = (const uint4*)wlds;
    float acc = 0.f;
#pragma unroll
    for (int j = 0; j < 16; ++j) {
        uint4 hv = hp[j];
        uint4 wv = wp[j];
        acc = dot2(hv.x, wv.x, acc);
        acc = dot2(hv.y, wv.y, acc);
        acc = dot2(hv.z, wv.z, acc);
        acc = dot2(hv.w, wv.w, acc);
    }
    out[idx] = ftanh(acc + fc_b[0]);
}

extern "C" void kernel_launch(void* const* d_in, const int* in_sizes, int n_in,
                              void* d_out, int out_size, void* d_ws, size_t ws_size,
                              hipStream_t stream) {
    const float* x    = (const float*)d_in[0];
    const float* W_ih = (const float*)d_in[1];
    const float* W_hh = (const float*)d_in[2];
    const float* b_ih = (const float*)d_in[3];
    const float* b_hh = (const float*)d_in[4];
    const float* fc_w = (const float*)d_in[5];
    const float* fc_b = (const float*)d_in[6];
    float* out = (float*)d_out;

    const size_t need = (size_t)NB * NT * NH * sizeof(_Float16);  // 128 MB
    if (ws_size >= need) {
        _Float16* hws = (_Float16*)d_ws;
        lstm_k1<true><<<dim3(NB), dim3(512), 0, stream>>>(
            x, W_ih, W_hh, b_ih, b_hh, fc_w, fc_b, out, hws);
        fc_k2<<<dim3(NB * NT / 256), dim3(256), 0, stream>>>(hws, fc_w, fc_b, out);
    } else {
        lstm_k1<false><<<dim3(NB), dim3(512), 0, stream>>>(
            x, W_ih, W_hh, b_ih, b_hh, fc_w, fc_b, out, nullptr);
    }
}

// Round 10
// 1159.605 us; speedup vs baseline: 1.4181x; 1.4181x over previous
//
#include <hip/hip_runtime.h>

// LSTM B=256, T=2048, H=128, gates 4H=512, deferred fc projection.
// Round-9 lesson: legacy v_mfma_f32_16x16x16_f16 is ~16 cyc/instr on gfx950
// (quarter-rate legacy shape): 64 MFMA/SIMD/step = 1060 cyc = the measured
// MfmaUtil 53%. The CDNA4-native 16x16x32_f16 is ~5 cyc AND double-K:
// 16 MFMA/wave/step at ~5 cyc -> MFMA issue drops ~6x.
//
// Layout-safety argument (why the packing is exact): we construct BOTH A and
// B fragments, and the HW uses the same (lane,elem)->k map for A and B. We
// store h[g(q,e)] at A-pos (q,e) and W_hh[row][g(q,e)] at B-pos (q,e) with
// g(q,e) = 32*kc + 8q + e; for ANY bijection g the dot is exactly
// sum_j h[j]*W[row][j]. D layout (m89-verified, dtype-independent):
// col=lane&15, row=(lane>>4)*4+reg -> batch-row 0 = lanes 0..15, reg 0.
//
// One batch row per WG (256 WGs), 512 threads = 8 waves; wave w owns gates
// [64w, 64w+64) = gate-type (w>>1), units (w&1)*64 + [0,64).
// Per step: 4 masked ds_read_b128 (A frags, lanes nlo==0) -> 16 MFMA
// (4 indep chains x 4 K-chunks) -> lanes<16: +bias +x*W_ih, activate
// (wave-uniform), write float4 g_lds[unit] components -> barrier ->
// t<128: 1 b128 gate read, cell update, h -> double-buffered h_lds fp16 +
// fire-and-forget global store -> barrier (both lgkmcnt-only, no vmcnt).

typedef _Float16 half2v __attribute__((ext_vector_type(2)));
typedef _Float16 f16x8  __attribute__((ext_vector_type(8)));
typedef float    f32x4  __attribute__((ext_vector_type(4)));

constexpr int NB = 256;
constexpr int NT = 2048;
constexpr int NH = 128;

__device__ __forceinline__ float fexp2(float x) {
    float r;
    asm("v_exp_f32 %0, %1" : "=v"(r) : "v"(x));
    return r;
}
__device__ __forceinline__ float frcp(float x) {
    float r;
    asm("v_rcp_f32 %0, %1" : "=v"(r) : "v"(x));
    return r;
}
__device__ __forceinline__ float fsig(float x) {   // 1/(1+2^(-x*log2e))
    return frcp(1.f + fexp2(x * -1.44269504f));
}
__device__ __forceinline__ float ftanh(float x) {  // 2/(1+2^(-2x*log2e)) - 1
    return fmaf(2.f, frcp(1.f + fexp2(x * -2.88539008f)), -1.f);
}

__device__ __forceinline__ unsigned packh2(float lo, float hi) {
    half2v p;
    p.x = (_Float16)lo;
    p.y = (_Float16)hi;
    return __builtin_bit_cast(unsigned, p);
}

__device__ __forceinline__ float dot2(unsigned int w, unsigned int h, float acc) {
    half2v a = __builtin_bit_cast(half2v, w);
    half2v b = __builtin_bit_cast(half2v, h);
#if __has_builtin(__builtin_amdgcn_fdot2)
    return __builtin_amdgcn_fdot2(a, b, acc, false);
#else
    float r;
    asm("v_dot2_f32_f16 %0, %1, %2, %3" : "=v"(r) : "v"(a), "v"(b), "v"(acc));
    return r;
#endif
}

__device__ __forceinline__ f32x4 mfma32(f16x8 a, f16x8 b, f32x4 c) {
#if __has_builtin(__builtin_amdgcn_mfma_f32_16x16x32_f16)
    return __builtin_amdgcn_mfma_f32_16x16x32_f16(a, b, c, 0, 0, 0);
#else
    asm("v_mfma_f32_16x16x32_f16 %0, %1, %2, %0" : "+v"(c) : "v"(a), "v"(b));
    return c;
#endif
}

// barrier with LDS visibility, NO vmcnt drain (fire-and-forget h stores
// stay off the 2048-iteration critical path)
__device__ __forceinline__ void barrier_lds() {
    asm volatile("s_waitcnt lgkmcnt(0)" ::: "memory");
    __builtin_amdgcn_s_barrier();
    asm volatile("" ::: "memory");
}

template <bool DEFER_FC>
__global__ __launch_bounds__(512, 2)
void lstm_k1(const float* __restrict__ x, const float* __restrict__ W_ih,
             const float* __restrict__ W_hh, const float* __restrict__ b_ih,
             const float* __restrict__ b_hh, const float* __restrict__ fc_w,
             const float* __restrict__ fc_b, float* __restrict__ out,
             _Float16* __restrict__ hws) {
    __shared__ __align__(16) float    x_lds[NT];
    __shared__ __align__(16) _Float16 h_lds[2][NH];  // double buffer
    __shared__ __align__(16) float4   gq[NH];        // per unit {i,f,z,o}
    __shared__ float red[2];                         // fallback fc partials

    const int b    = blockIdx.x;
    const int t    = threadIdx.x;   // 0..511
    const int lane = t & 63;
    const int w    = t >> 6;        // wave 0..7: gates [64w, 64w+64)
    const int q    = lane >> 4;     // k-subgroup 0..3
    const int nlo  = lane & 15;     // column-within-tile
    const int gtyp = w >> 1;        // gate type 0..3 (i,f,z,o)
    const int ubase = (w & 1) * 64; // unit base for this wave

    // preload x row (512 x float4)
    ((float4*)x_lds)[t] = ((const float4*)(x + (size_t)b * NT))[t];
    if (t < NH) h_lds[0][t] = (_Float16)0.f;

    // ---- persistent B-frags: 4 N-tiles x 4 K-chunks, f16x8 each ----
    // lane l, elem e of bw[tile][kc] = W_hh[64w+16*tile+nlo][32*kc+8q+e]
    f16x8 bw[4][4];
#pragma unroll
    for (int tile = 0; tile < 4; ++tile) {
        const float* wrow = W_hh + (size_t)(64 * w + 16 * tile + nlo) * NH;
#pragma unroll
        for (int kc = 0; kc < 4; ++kc) {
            float4 f0 = *(const float4*)(wrow + kc * 32 + q * 8);
            float4 f1 = *(const float4*)(wrow + kc * 32 + q * 8 + 4);
            f16x8 v;
            v[0] = (_Float16)f0.x; v[1] = (_Float16)f0.y;
            v[2] = (_Float16)f0.z; v[3] = (_Float16)f0.w;
            v[4] = (_Float16)f1.x; v[5] = (_Float16)f1.y;
            v[6] = (_Float16)f1.z; v[7] = (_Float16)f1.w;
            bw[tile][kc] = v;
        }
    }
#pragma unroll
    for (int tile = 0; tile < 4; ++tile)
#pragma unroll
        for (int kc = 0; kc < 4; ++kc) asm volatile("" : "+v"(bw[tile][kc]));

    // per-lane gate constants (extract lanes only): gate g = 64w+16*tile+lane
    float wih0 = 0.f, wih1 = 0.f, wih2 = 0.f, wih3 = 0.f;
    float bia0 = 0.f, bia1 = 0.f, bia2 = 0.f, bia3 = 0.f;
    if (lane < 16) {
        const int g0 = 64 * w + lane;
        wih0 = W_ih[g0];
        wih1 = W_ih[g0 + 16];
        wih2 = W_ih[g0 + 32];
        wih3 = W_ih[g0 + 48];
        bia0 = b_ih[g0] + b_hh[g0];
        bia1 = b_ih[g0 + 16] + b_hh[g0 + 16];
        bia2 = b_ih[g0 + 32] + b_hh[g0 + 32];
        bia3 = b_ih[g0 + 48] + b_hh[g0 + 48];
    }
    const bool is_tanh = (gtyp == 2);  // gates 256..383 = z

    float c = 0.f, h = 0.f;  // cell state: threads t<128 own unit u=t
    float fcw = 0.f, fcb = 0.f;
    if (!DEFER_FC && t < NH) {
        fcw = fc_w[t];
        fcb = fc_b[0];
    }

    float*    outp = out + (size_t)b * NT;
    _Float16* hrow = DEFER_FC ? (hws + (size_t)b * NT * NH) : (_Float16*)nullptr;

    // A-frags: zero except lanes nlo==0 (batch row 0), refreshed each step
    f16x8 av[4];
#pragma unroll
    for (int kc = 0; kc < 4; ++kc) av[kc] = f16x8{0, 0, 0, 0, 0, 0, 0, 0};

    __syncthreads();

    for (int step = 0; step < NT; ++step) {
        // ---- A-frag load: h[32kc+8q+e] on lanes nlo==0 (1 b128 per kc) ----
        const _Float16* hbuf = h_lds[step & 1];
        if (nlo == 0) {
#pragma unroll
            for (int kc = 0; kc < 4; ++kc)
                av[kc] = *(const f16x8*)(hbuf + kc * 32 + q * 8);
        }
        // ---- 16 MFMA: 4 independent accumulation chains x 4 K-chunks ----
        f32x4 a0 = {0.f, 0.f, 0.f, 0.f}, a1 = a0, a2 = a0, a3 = a0;
#pragma unroll
        for (int kc = 0; kc < 4; ++kc) {
            a0 = mfma32(av[kc], bw[0][kc], a0);
            a1 = mfma32(av[kc], bw[1][kc], a1);
            a2 = mfma32(av[kc], bw[2][kc], a2);
            a3 = mfma32(av[kc], bw[3][kc], a3);
        }
        // ---- extract row 0 (lanes 0..15, reg 0), activate, -> gq ----
        if (lane < 16) {
            float xv = x_lds[step];
            float v0 = fmaf(xv, wih0, a0[0] + bia0);
            float v1 = fmaf(xv, wih1, a1[0] + bia1);
            float v2 = fmaf(xv, wih2, a2[0] + bia2);
            float v3 = fmaf(xv, wih3, a3[0] + bia3);
            float r0, r1, r2, r3;
            if (is_tanh) {
                r0 = ftanh(v0); r1 = ftanh(v1); r2 = ftanh(v2); r3 = ftanh(v3);
            } else {
                r0 = fsig(v0);  r1 = fsig(v1);  r2 = fsig(v2);  r3 = fsig(v3);
            }
            // unit = ubase + 16*tile + lane, component = gtyp
            float* gp = (float*)gq;
            gp[(ubase + lane) * 4 + gtyp]      = r0;
            gp[(ubase + 16 + lane) * 4 + gtyp] = r1;
            gp[(ubase + 32 + lane) * 4 + gtyp] = r2;
            gp[(ubase + 48 + lane) * 4 + gtyp] = r3;
        }
        barrier_lds();

        // ---- cell update: thread t<128 owns unit u=t (1 b128 read) ----
        if (t < NH) {
            float4 gv = gq[t];  // {i,f,z,o}
            c = fmaf(gv.y, c, gv.x * gv.z);
            h = gv.w * ftanh(c);
            h_lds[(step + 1) & 1][t] = (_Float16)h;
            if (DEFER_FC) hrow[(size_t)step * NH + t] = (_Float16)h;
        }
        if (!DEFER_FC) {
            if (t < NH) {
                float p = h * fcw;
#pragma unroll
                for (int m = 32; m >= 1; m >>= 1) p += __shfl_xor(p, m, 64);
                if (lane == 0) red[t >> 6] = p;
            }
            __syncthreads();
            if (t == 0) outp[step] = ftanh(red[0] + red[1] + fcb);
        }
        barrier_lds();
    }

    // ---- final hT, cT ([1,B,H] each, after out) ----
    if (t < NH) {
        float* hT = out + (size_t)NB * NT;
        float* cT = hT + (size_t)NB * NH;
        hT[b * NH + t] = h;
        cT[b * NH + t] = c;
    }
}

// Kernel 2: out[b,t] = tanh(dot(h[b,t,:], fc_w) + fc_b). Memory-bound.
__global__ __launch_bounds__(256) void fc_k2(const _Float16* __restrict__ hws,
                                             const float* __restrict__ fc_w,
                                             const float* __restrict__ fc_b,
                                             float* __restrict__ out) {
    __shared__ unsigned wlds[64];
    const int t = threadIdx.x;
    if (t < 64) {
        float2 f = ((const float2*)fc_w)[t];
        wlds[t] = packh2(f.x, f.y);
    }
    __syncthreads();

    const size_t idx = (size_t)blockIdx.x * 256 + t;
    const uint4* hp = (const uint4*)(hws + idx * NH);
    const uint4* wp = (const uint4*)wlds;
    float acc = 0.f;
#pragma unroll
    for (int j = 0; j < 16; ++j) {
        uint4 hv = hp[j];
        uint4 wv = wp[j];
        acc = dot2(hv.x, wv.x, acc);
        acc = dot2(hv.y, wv.y, acc);
        acc = dot2(hv.z, wv.z, acc);
        acc = dot2(hv.w, wv.w, acc);
    }
    out[idx] = ftanh(acc + fc_b[0]);
}

extern "C" void kernel_launch(void* const* d_in, const int* in_sizes, int n_in,
                              void* d_out, int out_size, void* d_ws, size_t ws_size,
                              hipStream_t stream) {
    const float* x    = (const float*)d_in[0];
    const float* W_ih = (const float*)d_in[1];
    const float* W_hh = (const float*)d_in[2];
    const float* b_ih = (const float*)d_in[3];
    const float* b_hh = (const float*)d_in[4];
    const float* fc_w = (const float*)d_in[5];
    const float* fc_b = (const float*)d_in[6];
    float* out = (float*)d_out;

    const size_t need = (size_t)NB * NT * NH * sizeof(_Float16);  // 128 MB
    if (ws_size >= need) {
        _Float16* hws = (_Float16*)d_ws;
        lstm_k1<true><<<dim3(NB), dim3(512), 0, stream>>>(
            x, W_ih, W_hh, b_ih, b_hh, fc_w, fc_b, out, hws);
        fc_k2<<<dim3(NB * NT / 256), dim3(256), 0, stream>>>(hws, fc_w, fc_b, out);
    } else {
        lstm_k1<false><<<dim3(NB), dim3(512), 0, stream>>>(
            x, W_ih, W_hh, b_ih, b_hh, fc_w, fc_b, out, nullptr);
    }
}

// Round 11
// 937.764 us; speedup vs baseline: 1.7536x; 1.2366x over previous
//
#include <hip/hip_runtime.h>

// LSTM B=256, T=2048, H=128, gates 4H=512, deferred fc projection.
// Round-10 lesson: MFMA-pipe busy (534 cyc) is near the per-CU floor for a
// matvec (128 MFMA/CU/step, M=1/16 used — structural, B=256=CU count), but
// ~430 cyc/step went to the gq gate-exchange (2nd barrier + 120-cyc LDS
// round-trip + 1.7e7 bank conflicts).
// This round: wave w owns UNITS [16w,16w+16) with ALL FOUR gate types
// (N-tiles = rows {g*128+16w+nlo}). D row 0 of the 4 acc chains gives lane
// nlo its unit's complete {i,f,z,o} -> cell update fully in-wave/in-reg.
// No gq buffer, ONE barrier/step, zero conflict surfaces.
// A-frags are loaded UNMASKED (all lanes read the same h chunk -> LDS
// broadcast): all 16 A-rows = h, so all D rows are identical and every lane
// holds its unit's gates — no exec-mask dance, activations on all lanes
// (4x redundant across q-groups, same wave cost).
//
// mfma_f32_16x16x32_f16 packing safety: A[q,e] = h[32kc+8q+e] and
// B[q,e] = W_hh[row][32kc+8q+e] use the SAME (lane,elem)->k map, so the
// contraction is exact for any bijection. D: col=lane&15, row=(lane>>4)*4+reg
// (m89-verified, dtype-independent) -> row 0 = reg 0, replicated here.

typedef _Float16 half2v __attribute__((ext_vector_type(2)));
typedef _Float16 f16x8  __attribute__((ext_vector_type(8)));
typedef float    f32x4  __attribute__((ext_vector_type(4)));

constexpr int NB = 256;
constexpr int NT = 2048;
constexpr int NH = 128;

__device__ __forceinline__ float fexp2(float x) {
    float r;
    asm("v_exp_f32 %0, %1" : "=v"(r) : "v"(x));
    return r;
}
__device__ __forceinline__ float frcp(float x) {
    float r;
    asm("v_rcp_f32 %0, %1" : "=v"(r) : "v"(x));
    return r;
}
__device__ __forceinline__ float fsig(float x) {   // 1/(1+2^(-x*log2e))
    return frcp(1.f + fexp2(x * -1.44269504f));
}
__device__ __forceinline__ float ftanh(float x) {  // 2/(1+2^(-2x*log2e)) - 1
    return fmaf(2.f, frcp(1.f + fexp2(x * -2.88539008f)), -1.f);
}

__device__ __forceinline__ unsigned packh2(float lo, float hi) {
    half2v p;
    p.x = (_Float16)lo;
    p.y = (_Float16)hi;
    return __builtin_bit_cast(unsigned, p);
}

__device__ __forceinline__ float dot2(unsigned int w, unsigned int h, float acc) {
    half2v a = __builtin_bit_cast(half2v, w);
    half2v b = __builtin_bit_cast(half2v, h);
#if __has_builtin(__builtin_amdgcn_fdot2)
    return __builtin_amdgcn_fdot2(a, b, acc, false);
#else
    float r;
    asm("v_dot2_f32_f16 %0, %1, %2, %3" : "=v"(r) : "v"(a), "v"(b), "v"(acc));
    return r;
#endif
}

__device__ __forceinline__ f32x4 mfma32(f16x8 a, f16x8 b, f32x4 c) {
#if __has_builtin(__builtin_amdgcn_mfma_f32_16x16x32_f16)
    return __builtin_amdgcn_mfma_f32_16x16x32_f16(a, b, c, 0, 0, 0);
#else
    asm("v_mfma_f32_16x16x32_f16 %0, %1, %2, %0" : "+v"(c) : "v"(a), "v"(b));
    return c;
#endif
}

// barrier with LDS visibility, NO vmcnt drain (fire-and-forget h stores
// stay off the 2048-iteration critical path)
__device__ __forceinline__ void barrier_lds() {
    asm volatile("s_waitcnt lgkmcnt(0)" ::: "memory");
    __builtin_amdgcn_s_barrier();
    asm volatile("" ::: "memory");
}

template <bool DEFER_FC>
__global__ __launch_bounds__(512, 2)
void lstm_k1(const float* __restrict__ x, const float* __restrict__ W_ih,
             const float* __restrict__ W_hh, const float* __restrict__ b_ih,
             const float* __restrict__ b_hh, const float* __restrict__ fc_w,
             const float* __restrict__ fc_b, float* __restrict__ out,
             _Float16* __restrict__ hws) {
    __shared__ __align__(16) float    x_lds[NT];
    __shared__ __align__(16) _Float16 h_lds[2][NH];  // double buffer
    __shared__ float red[8];                         // fallback fc partials

    const int b    = blockIdx.x;
    const int t    = threadIdx.x;   // 0..511
    const int lane = t & 63;
    const int w    = t >> 6;        // wave 0..7: units [16w, 16w+16)
    const int q    = lane >> 4;     // k-subgroup 0..3
    const int nlo  = lane & 15;     // unit-within-wave
    const int u    = 16 * w + nlo;  // this lane's hidden unit

    // preload x row (512 x float4)
    ((float4*)x_lds)[t] = ((const float4*)(x + (size_t)b * NT))[t];
    if (t < NH) h_lds[0][t] = (_Float16)0.f;

    // ---- persistent B-frags: 4 gate-type tiles x 4 K-chunks, f16x8 ----
    // lane l, elem e of bw[g][kc] = W_hh[g*NH + u][32*kc + 8q + e]
    f16x8 bw[4][4];
#pragma unroll
    for (int g = 0; g < 4; ++g) {
        const float* wrow = W_hh + (size_t)(g * NH + u) * NH;
#pragma unroll
        for (int kc = 0; kc < 4; ++kc) {
            float4 f0 = *(const float4*)(wrow + kc * 32 + q * 8);
            float4 f1 = *(const float4*)(wrow + kc * 32 + q * 8 + 4);
            f16x8 v;
            v[0] = (_Float16)f0.x; v[1] = (_Float16)f0.y;
            v[2] = (_Float16)f0.z; v[3] = (_Float16)f0.w;
            v[4] = (_Float16)f1.x; v[5] = (_Float16)f1.y;
            v[6] = (_Float16)f1.z; v[7] = (_Float16)f1.w;
            bw[g][kc] = v;
        }
    }
#pragma unroll
    for (int g = 0; g < 4; ++g)
#pragma unroll
        for (int kc = 0; kc < 4; ++kc) asm volatile("" : "+v"(bw[g][kc]));

    // per-lane gate constants for unit u (all lanes; replicated across q)
    const float bi = b_ih[u] + b_hh[u];
    const float bf = b_ih[NH + u] + b_hh[NH + u];
    const float bz = b_ih[2 * NH + u] + b_hh[2 * NH + u];
    const float bo = b_ih[3 * NH + u] + b_hh[3 * NH + u];
    const float wi = W_ih[u];
    const float wf = W_ih[NH + u];
    const float wz = W_ih[2 * NH + u];
    const float wo = W_ih[3 * NH + u];

    float c = 0.f, h = 0.f;  // cell state of unit u (replicated across q)
    float fcw = 0.f, fcb = 0.f;
    if (!DEFER_FC) {
        fcw = fc_w[u];
        fcb = fc_b[0];
    }

    float*    outp = out + (size_t)b * NT;
    _Float16* hrow = DEFER_FC ? (hws + (size_t)b * NT * NH) : (_Float16*)nullptr;

    __syncthreads();

    for (int step = 0; step < NT; ++step) {
        // ---- A-frags: uniform broadcast reads, all 16 A-rows = h ----
        const _Float16* hbuf = h_lds[step & 1];
        f16x8 av[4];
#pragma unroll
        for (int kc = 0; kc < 4; ++kc)
            av[kc] = *(const f16x8*)(hbuf + kc * 32 + q * 8);

        // ---- 16 MFMA: 4 gate-type chains x 4 K-chunks ----
        f32x4 a0 = {0.f, 0.f, 0.f, 0.f}, a1 = a0, a2 = a0, a3 = a0;
#pragma unroll
        for (int kc = 0; kc < 4; ++kc) {
            a0 = mfma32(av[kc], bw[0][kc], a0);
            a1 = mfma32(av[kc], bw[1][kc], a1);
            a2 = mfma32(av[kc], bw[2][kc], a2);
            a3 = mfma32(av[kc], bw[3][kc], a3);
        }

        // ---- all rows identical -> reg 0 holds gate[u] on every lane ----
        float xv = x_lds[step];
        float gi = fsig(fmaf(xv, wi, a0[0] + bi));
        float gf = fsig(fmaf(xv, wf, a1[0] + bf));
        float gz = ftanh(fmaf(xv, wz, a2[0] + bz));
        float go = fsig(fmaf(xv, wo, a3[0] + bo));

        // ---- in-wave cell update (no gate exchange, no extra barrier) ----
        c = fmaf(gf, c, gi * gz);
        h = go * ftanh(c);
        if (lane < 16) {
            h_lds[(step + 1) & 1][u] = (_Float16)h;
            if (DEFER_FC) hrow[(size_t)step * NH + u] = (_Float16)h;
        }
        if (!DEFER_FC) {
            float p = (lane < 16) ? h * fcw : 0.f;
#pragma unroll
            for (int m = 8; m >= 1; m >>= 1) p += __shfl_xor(p, m, 64);
            if (lane == 0) red[w] = p;
            __syncthreads();
            if (t == 0) {
                float s = red[0] + red[1] + red[2] + red[3] + red[4] + red[5] +
                          red[6] + red[7];
                outp[step] = ftanh(s + fcb);
            }
        }
        barrier_lds();  // h_lds[next] visible to all waves
    }

    // ---- final hT, cT ([1,B,H] each, after out) ----
    if (lane < 16) {
        float* hT = out + (size_t)NB * NT;
        float* cT = hT + (size_t)NB * NH;
        hT[b * NH + u] = h;
        cT[b * NH + u] = c;
    }
}

// Kernel 2: out[b,t] = tanh(dot(h[b,t,:], fc_w) + fc_b). Memory-bound.
__global__ __launch_bounds__(256) void fc_k2(const _Float16* __restrict__ hws,
                                             const float* __restrict__ fc_w,
                                             const float* __restrict__ fc_b,
                                             float* __restrict__ out) {
    __shared__ unsigned wlds[64];
    const int t = threadIdx.x;
    if (t < 64) {
        float2 f = ((const float2*)fc_w)[t];
        wlds[t] = packh2(f.x, f.y);
    }
    __syncthreads();

    const size_t idx = (size_t)blockIdx.x * 256 + t;
    const uint4* hp = (const uint4*)(hws + idx * NH);
    const uint4* wp = (const uint4*)wlds;
    float acc = 0.f;
#pragma unroll
    for (int j = 0; j < 16; ++j) {
        uint4 hv = hp[j];
        uint4 wv = wp[j];
        acc = dot2(hv.x, wv.x, acc);
        acc = dot2(hv.y, wv.y, acc);
        acc = dot2(hv.z, wv.z, acc);
        acc = dot2(hv.w, wv.w, acc);
    }
    out[idx] = ftanh(acc + fc_b[0]);
}

extern "C" void kernel_launch(void* const* d_in, const int* in_sizes, int n_in,
                              void* d_out, int out_size, void* d_ws, size_t ws_size,
                              hipStream_t stream) {
    const float* x    = (const float*)d_in[0];
    const float* W_ih = (const float*)d_in[1];
    const float* W_hh = (const float*)d_in[2];
    const float* b_ih = (const float*)d_in[3];
    const float* b_hh = (const float*)d_in[4];
    const float* fc_w = (const float*)d_in[5];
    const float* fc_b = (const float*)d_in[6];
    float* out = (float*)d_out;

    const size_t need = (size_t)NB * NT * NH * sizeof(_Float16);  // 128 MB
    if (ws_size >= need) {
        _Float16* hws = (_Float16*)d_ws;
        lstm_k1<true><<<dim3(NB), dim3(512), 0, stream>>>(
            x, W_ih, W_hh, b_ih, b_hh, fc_w, fc_b, out, hws);
        fc_k2<<<dim3(NB * NT / 256), dim3(256), 0, stream>>>(hws, fc_w, fc_b, out);
    } else {
        lstm_k1<false><<<dim3(NB), dim3(512), 0, stream>>>(
            x, W_ih, W_hh, b_ih, b_hh, fc_w, fc_b, out, nullptr);
    }
}